// Round 2
// baseline (340.927 us; speedup 1.0000x reference)
//
#include <hip/hip_runtime.h>

#define L  768
#define SD 384
#define PD 128
#define ROWS 4   // rows per phase1 block
#define TI 16    // i-tile per phase2 block
#define TJ 16    // j-tile per phase2 block

typedef float vf4 __attribute__((ext_vector_type(4)));

// ws layout (floats): si[L*PD] | sj[L*PD] | u[L*PD] | v[L*PD]   (1.57 MB total)

__global__ __launch_bounds__(256) void phase1_kernel(
    const float* __restrict__ s,
    const float* __restrict__ wi, const float* __restrict__ bi,
    const float* __restrict__ wj, const float* __restrict__ bj,
    const float* __restrict__ wm, const float* __restrict__ bm,
    float* __restrict__ ws)
{
    __shared__ float s_t[ROWS][SD];          // 6 KB
    __shared__ float sij_t[2][ROWS][PD];     // 4 KB
    const int tid = threadIdx.x;
    const int r0  = blockIdx.x * ROWS;

    // stage 4 rows of s into LDS, coalesced
    for (int idx = tid; idx < ROWS * SD; idx += 256) {
        s_t[idx / SD][idx % SD] = s[(size_t)r0 * SD + idx];
    }
    __syncthreads();

    const int half = tid >> 7;        // wave-uniform: waves 0-1 -> si, waves 2-3 -> sj
    const int e    = tid & 127;       // output channel
    const float* wrow = (half ? wj : wi) + (size_t)e * SD;
    const float  bb   = (half ? bj : bi)[e];

    // si[r][e] / sj[r][e] = dot(s[r], w[e]) + b[e]
    float acc[ROWS] = {0.f, 0.f, 0.f, 0.f};
    const vf4* w4 = (const vf4*)wrow;
    for (int d4 = 0; d4 < SD / 4; ++d4) {
        const vf4 wv = w4[d4];
        #pragma unroll
        for (int r = 0; r < ROWS; ++r) {
            const vf4 sv = ((const vf4*)s_t[r])[d4];   // LDS broadcast, b128
            acc[r] += sv.x * wv.x + sv.y * wv.y + sv.z * wv.z + sv.w * wv.w;
        }
    }

    float* si_ws = ws;
    float* sj_ws = ws + (size_t)L * PD;
    float* u_ws  = ws + 2 * (size_t)L * PD;
    float* v_ws  = ws + 3 * (size_t)L * PD;

    float* sij_ws = half ? sj_ws : si_ws;
    #pragma unroll
    for (int r = 0; r < ROWS; ++r) {
        const float val = acc[r] + bb;
        sij_t[half][r][e] = val;
        sij_ws[(size_t)(r0 + r) * PD + e] = val;
    }
    __syncthreads();

    // u[r][e] = dot(si[r], wm[e, 0:128]) ; v[r][e] = dot(sj[r], wm[e, 128:256]) + bm[e]
    const vf4* wm4 = (const vf4*)(wm + (size_t)e * (2 * PD) + half * PD);
    float acc2[ROWS] = {0.f, 0.f, 0.f, 0.f};
    for (int d4 = 0; d4 < PD / 4; ++d4) {
        const vf4 wv = wm4[d4];
        #pragma unroll
        for (int r = 0; r < ROWS; ++r) {
            const vf4 sv = ((const vf4*)sij_t[half][r])[d4];
            acc2[r] += sv.x * wv.x + sv.y * wv.y + sv.z * wv.z + sv.w * wv.w;
        }
    }
    const float bm_e = bm[e];
    float* z_ws = half ? v_ws : u_ws;
    #pragma unroll
    for (int r = 0; r < ROWS; ++r) {
        z_ws[(size_t)(r0 + r) * PD + e] = acc2[r] + (half ? bm_e : 0.f);
    }
}

// out[i,j,e] = u[i,e] + v[j,e] + si[i,e]*sj[j,e]
// block: 256 threads = 8 groups (g) x 32 channel-float4s (q); tile TI x TJ pairs.
// thread (g,q): owns j in {j0+2g, j0+2g+1}, loops over 16 i's.
__global__ __launch_bounds__(256) void phase2_kernel(
    const float* __restrict__ ws, float* __restrict__ out)
{
    const int i0 = blockIdx.y * TI;
    const int j0 = blockIdx.x * TJ;
    const int q  = threadIdx.x & 31;   // float4 index within 128 channels
    const int g  = threadIdx.x >> 5;   // 0..7

    const vf4* si = (const vf4*)(ws);
    const vf4* sj = (const vf4*)(ws + (size_t)L * PD);
    const vf4* u  = (const vf4*)(ws + 2 * (size_t)L * PD);
    const vf4* v  = (const vf4*)(ws + 3 * (size_t)L * PD);

    const int j1 = j0 + g * 2;
    const vf4 vj0  = v[(size_t)j1 * 32 + q];
    const vf4 vj1  = v[(size_t)(j1 + 1) * 32 + q];
    const vf4 sjj0 = sj[(size_t)j1 * 32 + q];
    const vf4 sjj1 = sj[(size_t)(j1 + 1) * 32 + q];

    vf4* o = (vf4*)out;
    for (int il = 0; il < TI; ++il) {
        const int i = i0 + il;
        const vf4 s4 = si[(size_t)i * 32 + q];
        const vf4 u4 = u[(size_t)i * 32 + q];
        const size_t base = ((size_t)i * L + j1) * 32 + q;

        const vf4 r0 = u4 + vj0 + s4 * sjj0;
        const vf4 r1 = u4 + vj1 + s4 * sjj1;
        __builtin_nontemporal_store(r0, &o[base]);
        __builtin_nontemporal_store(r1, &o[base + 32]);
    }
}

extern "C" void kernel_launch(void* const* d_in, const int* in_sizes, int n_in,
                              void* d_out, int out_size, void* d_ws, size_t ws_size,
                              hipStream_t stream) {
    const float* s  = (const float*)d_in[0];
    const float* wi = (const float*)d_in[1];
    const float* bi = (const float*)d_in[2];
    const float* wj = (const float*)d_in[3];
    const float* bj = (const float*)d_in[4];
    const float* wm = (const float*)d_in[5];
    const float* bm = (const float*)d_in[6];
    float* out = (float*)d_out;
    float* ws  = (float*)d_ws;   // needs 4*L*PD*4 = 1.57 MB

    phase1_kernel<<<dim3(L / ROWS), 256, 0, stream>>>(s, wi, bi, wj, bj, wm, bm, ws);
    phase2_kernel<<<dim3(L / TJ, L / TI), 256, 0, stream>>>(ws, out);
}

// Round 3
// 339.372 us; speedup vs baseline: 1.0046x; 1.0046x over previous
//
#include <hip/hip_runtime.h>

#define L  768
#define SD 384
#define PD 128
#define ROWS 4   // rows per phase1 block
#define TI 32    // i-tile per phase2 block
#define TJ 8     // j-tile per phase2 block

typedef float vf4 __attribute__((ext_vector_type(4)));

// ws layout (floats): si[L*PD] | sj[L*PD] | u[L*PD] | v[L*PD]   (1.57 MB total)

__global__ __launch_bounds__(256) void phase1_kernel(
    const float* __restrict__ s,
    const float* __restrict__ wi, const float* __restrict__ bi,
    const float* __restrict__ wj, const float* __restrict__ bj,
    const float* __restrict__ wm, const float* __restrict__ bm,
    float* __restrict__ ws)
{
    __shared__ float s_t[ROWS][SD];          // 6 KB
    __shared__ float sij_t[2][ROWS][PD];     // 4 KB
    const int tid = threadIdx.x;
    const int r0  = blockIdx.x * ROWS;

    // stage 4 rows of s into LDS, coalesced
    for (int idx = tid; idx < ROWS * SD; idx += 256) {
        s_t[idx / SD][idx % SD] = s[(size_t)r0 * SD + idx];
    }
    __syncthreads();

    const int half = tid >> 7;        // wave-uniform: waves 0-1 -> si, waves 2-3 -> sj
    const int e    = tid & 127;       // output channel
    const float* wrow = (half ? wj : wi) + (size_t)e * SD;
    const float  bb   = (half ? bj : bi)[e];

    // si[r][e] / sj[r][e] = dot(s[r], w[e]) + b[e]
    float acc[ROWS] = {0.f, 0.f, 0.f, 0.f};
    const vf4* w4 = (const vf4*)wrow;
    for (int d4 = 0; d4 < SD / 4; ++d4) {
        const vf4 wv = w4[d4];
        #pragma unroll
        for (int r = 0; r < ROWS; ++r) {
            const vf4 sv = ((const vf4*)s_t[r])[d4];   // LDS broadcast, b128
            acc[r] += sv.x * wv.x + sv.y * wv.y + sv.z * wv.z + sv.w * wv.w;
        }
    }

    float* si_ws = ws;
    float* sj_ws = ws + (size_t)L * PD;
    float* u_ws  = ws + 2 * (size_t)L * PD;
    float* v_ws  = ws + 3 * (size_t)L * PD;

    float* sij_ws = half ? sj_ws : si_ws;
    #pragma unroll
    for (int r = 0; r < ROWS; ++r) {
        const float val = acc[r] + bb;
        sij_t[half][r][e] = val;
        sij_ws[(size_t)(r0 + r) * PD + e] = val;
    }
    __syncthreads();

    // u[r][e] = dot(si[r], wm[e, 0:128]) ; v[r][e] = dot(sj[r], wm[e, 128:256]) + bm[e]
    const vf4* wm4 = (const vf4*)(wm + (size_t)e * (2 * PD) + half * PD);
    float acc2[ROWS] = {0.f, 0.f, 0.f, 0.f};
    for (int d4 = 0; d4 < PD / 4; ++d4) {
        const vf4 wv = wm4[d4];
        #pragma unroll
        for (int r = 0; r < ROWS; ++r) {
            const vf4 sv = ((const vf4*)sij_t[half][r])[d4];
            acc2[r] += sv.x * wv.x + sv.y * wv.y + sv.z * wv.z + sv.w * wv.w;
        }
    }
    const float bm_e = bm[e];
    float* z_ws = half ? v_ws : u_ws;
    #pragma unroll
    for (int r = 0; r < ROWS; ++r) {
        z_ws[(size_t)(r0 + r) * PD + e] = acc2[r] + (half ? bm_e : 0.f);
    }
}

// out[i,j,e] = u[i,e] + v[j,e] + si[i,e]*sj[j,e]
// block: 256 threads = 8 j-rows (jj) x 32 channel-float4s (q); tile TI x TJ pairs.
// A wave (64 lanes) = 2 consecutive j-rows -> each store instruction covers a
// fully-contiguous 1 KB segment (matches the 6.4 TB/s fill-kernel pattern).
// Plain cached stores (no nt): let L2/L3 absorb the write stream.
__global__ __launch_bounds__(256) void phase2_kernel(
    const float* __restrict__ ws, float* __restrict__ out)
{
    const int i0 = blockIdx.y * TI;
    const int j0 = blockIdx.x * TJ;
    const int q  = threadIdx.x & 31;   // float4 index within 128 channels
    const int jj = threadIdx.x >> 5;   // 0..7

    const vf4* si = (const vf4*)(ws);
    const vf4* sj = (const vf4*)(ws + (size_t)L * PD);
    const vf4* u  = (const vf4*)(ws + 2 * (size_t)L * PD);
    const vf4* v  = (const vf4*)(ws + 3 * (size_t)L * PD);

    const int j = j0 + jj;
    const vf4 vj  = v[(size_t)j * 32 + q];
    const vf4 sjj = sj[(size_t)j * 32 + q];

    vf4* o = (vf4*)out;
    #pragma unroll 4
    for (int il = 0; il < TI; ++il) {
        const int i = i0 + il;
        const vf4 s4 = si[(size_t)i * 32 + q];
        const vf4 u4 = u[(size_t)i * 32 + q];
        o[((size_t)i * L + j) * 32 + q] = u4 + vj + s4 * sjj;
    }
}

extern "C" void kernel_launch(void* const* d_in, const int* in_sizes, int n_in,
                              void* d_out, int out_size, void* d_ws, size_t ws_size,
                              hipStream_t stream) {
    const float* s  = (const float*)d_in[0];
    const float* wi = (const float*)d_in[1];
    const float* bi = (const float*)d_in[2];
    const float* wj = (const float*)d_in[3];
    const float* bj = (const float*)d_in[4];
    const float* wm = (const float*)d_in[5];
    const float* bm = (const float*)d_in[6];
    float* out = (float*)d_out;
    float* ws  = (float*)d_ws;   // needs 4*L*PD*4 = 1.57 MB

    phase1_kernel<<<dim3(L / ROWS), 256, 0, stream>>>(s, wi, bi, wj, bj, wm, bm, ws);
    phase2_kernel<<<dim3(L / TJ, L / TI), 256, 0, stream>>>(ws, out);
}